// Round 18
// baseline (712.585 us; speedup 1.0000x reference)
//
#include <hip/hip_runtime.h>
#include <hip/hip_fp16.h>

#define N_NODES 50000
#define N_EDGES 600000
#define IN_F 16
#define HF 128
#define NC 4
#define NHL 19
#define WS_STRIDE 136   // f16 rows: 128 f16 + 8 pad = 272 B
#define W8_STRIDE 136   // fp8 rows: 128 B + 8 pad

__device__ __forceinline__ float lrelu(float x) { return x > 0.f ? x : 0.01f * x; }

struct h4 { __half2 a, b; };  // 8 bytes = 4 fp16 feats

typedef _Float16 f16;
typedef _Float16 f16x8 __attribute__((ext_vector_type(8)));
typedef float    f32x4 __attribute__((ext_vector_type(4)));
typedef float    f32x2 __attribute__((ext_vector_type(2)));

__device__ __forceinline__ unsigned pack_fp8x4(float a, float b, float c, float d) {
    int r = __builtin_amdgcn_cvt_pk_fp8_f32(a, b, 0, false);
    r = __builtin_amdgcn_cvt_pk_fp8_f32(c, d, r, true);
    return (unsigned)r;
}

// ---------------- CSR build ----------------

__global__ void count_deg_k(const int* __restrict__ dst, int* __restrict__ cnt) {
    int e = blockIdx.x * 256 + threadIdx.x;
    if (e < N_EDGES) atomicAdd(&cnt[dst[e]], 1);
}

// single-block exclusive scan via wave shuffles; also emits dinv
__global__ void scan_k(const int* __restrict__ cnt, int* __restrict__ rowptr,
                       float* __restrict__ dinv) {
    __shared__ int wsum[16];
    __shared__ int carry_s;
    int t = threadIdx.x;
    int lane = t & 63, wid = t >> 6;
    if (t == 0) carry_s = 0;
    __syncthreads();
    for (int base = 0; base < N_NODES; base += 4096) {
        int idx = base + t * 4;
        int4 v = make_int4(0, 0, 0, 0);
        if (idx + 3 < N_NODES) v = *(const int4*)&cnt[idx];
        else {
            if (idx     < N_NODES) v.x = cnt[idx];
            if (idx + 1 < N_NODES) v.y = cnt[idx + 1];
            if (idx + 2 < N_NODES) v.z = cnt[idx + 2];
            if (idx + 3 < N_NODES) v.w = cnt[idx + 3];
        }
        if (idx + 3 < N_NODES) {
            float4 dv = make_float4(1.f / fmaxf((float)v.x, 1.f), 1.f / fmaxf((float)v.y, 1.f),
                                    1.f / fmaxf((float)v.z, 1.f), 1.f / fmaxf((float)v.w, 1.f));
            *(float4*)&dinv[idx] = dv;
        } else {
            if (idx     < N_NODES) dinv[idx]     = 1.f / fmaxf((float)v.x, 1.f);
            if (idx + 1 < N_NODES) dinv[idx + 1] = 1.f / fmaxf((float)v.y, 1.f);
            if (idx + 2 < N_NODES) dinv[idx + 2] = 1.f / fmaxf((float)v.z, 1.f);
            if (idx + 3 < N_NODES) dinv[idx + 3] = 1.f / fmaxf((float)v.w, 1.f);
        }
        int s1 = v.x + v.y, s2 = s1 + v.z, total = s2 + v.w;
        int sc = total;
#pragma unroll
        for (int off = 1; off < 64; off <<= 1) {
            int u = __shfl_up(sc, off, 64);
            if (lane >= off) sc += u;
        }
        if (lane == 63) wsum[wid] = sc;
        __syncthreads();
        if (t < 16) {
            int w = wsum[t];
#pragma unroll
            for (int off = 1; off < 16; off <<= 1) {
                int u = __shfl_up(w, off, 64);
                if (t >= off) w += u;
            }
            wsum[t] = w;
        }
        __syncthreads();
        int prefix = carry_s + (wid > 0 ? wsum[wid - 1] : 0) + (sc - total);
        if (idx     < N_NODES) rowptr[idx]     = prefix;
        if (idx + 1 < N_NODES) rowptr[idx + 1] = prefix + v.x;
        if (idx + 2 < N_NODES) rowptr[idx + 2] = prefix + s1;
        if (idx + 3 < N_NODES) rowptr[idx + 3] = prefix + s2;
        __syncthreads();
        if (t == 0) carry_s += wsum[15];
        __syncthreads();
    }
    if (t == 0) rowptr[N_NODES] = carry_s;
}

// fill CSR: one 4-byte record {src:u16, w:fp16} per edge
__global__ void fill_k(const int* __restrict__ src, const int* __restrict__ dst,
                       const float* __restrict__ ea, const int* __restrict__ rowptr,
                       int* __restrict__ fill, unsigned* __restrict__ edg,
                       const float* __restrict__ dinv) {
    int e = blockIdx.x * 256 + threadIdx.x;
    if (e < N_EDGES) {
        int d = dst[e];
        float w = ea[e] * dinv[d];
        int pos = rowptr[d] + atomicAdd(&fill[d], 1);
        unsigned hw = (unsigned)__half_as_ushort(__float2half(w));
        edg[pos] = (unsigned)src[e] | (hw << 16);
    }
}

// ---------------- W converts ----------------
// Wt (fp16 [l][n][k]) for layers 17,18; W8 (fp8 [l][n][k]) for layers 0..16.

__global__ void wconv_k(const float* __restrict__ Wh, __half* __restrict__ Wt) {
    int idx = blockIdx.x * 256 + threadIdx.x;
    if (idx >= NHL * HF * HF) return;
    int l = idx / (HF * HF);
    int r = idx - l * (HF * HF);
    int n = r >> 7;
    int k = r & 127;
    Wt[idx] = __float2half(Wh[(size_t)l * HF * HF + k * HF + n]);
}

__global__ void wconv8_k(const float* __restrict__ Wh, unsigned* __restrict__ W8) {
    int idx = blockIdx.x * 256 + threadIdx.x;
    if (idx >= NHL * HF * HF / 4) return;
    int l = idx / (HF * HF / 4);
    int r = idx - l * (HF * HF / 4);
    int n  = r >> 5;
    int k4 = (r & 31) * 4;
    const float* Wl = Wh + (size_t)l * HF * HF;
    W8[idx] = pack_fp8x4(Wl[(k4 + 0) * HF + n], Wl[(k4 + 1) * HF + n],
                         Wl[(k4 + 2) * HF + n], Wl[(k4 + 3) * HF + n]);
}

// ---------------- input GEMM: T8[50000x128](fp8) = X[50000x16] @ W[16x128] + b ----------------

__global__ void gemm_in_k(const float* __restrict__ X, const float* __restrict__ W,
                          const float* __restrict__ b, unsigned* __restrict__ T8) {
    __shared__ float Ws[IN_F * HF];  // 8 KB
    int t = threadIdx.x;
    ((float4*)Ws)[t]       = ((const float4*)W)[t];
    ((float4*)Ws)[t + 256] = ((const float4*)W)[t + 256];
    __syncthreads();
    int row = blockIdx.x * 16 + (t >> 4);
    if (row >= N_NODES) return;
    int tx = t & 15;
    int c0 = tx * 4, c1 = 64 + tx * 4;
    float4 a0 = *(const float4*)&b[c0];
    float4 a1 = *(const float4*)&b[c1];
    const float4* xr = (const float4*)(X + row * IN_F);
#pragma unroll
    for (int k4 = 0; k4 < 4; k4++) {
        float4 xv = xr[k4];
        const float* xp = (const float*)&xv;
#pragma unroll
        for (int kk = 0; kk < 4; kk++) {
            int k = k4 * 4 + kk;
            float4 w0 = *(const float4*)&Ws[k * HF + c0];
            float4 w1 = *(const float4*)&Ws[k * HF + c1];
            float xs = xp[kk];
            a0.x = fmaf(xs, w0.x, a0.x); a0.y = fmaf(xs, w0.y, a0.y);
            a0.z = fmaf(xs, w0.z, a0.z); a0.w = fmaf(xs, w0.w, a0.w);
            a1.x = fmaf(xs, w1.x, a1.x); a1.y = fmaf(xs, w1.y, a1.y);
            a1.z = fmaf(xs, w1.z, a1.z); a1.w = fmaf(xs, w1.w, a1.w);
        }
    }
    T8[(size_t)row * 32 + tx]      = pack_fp8x4(a0.x, a0.y, a0.z, a0.w);
    T8[(size_t)row * 32 + 16 + tx] = pack_fp8x4(a1.x, a1.y, a1.z, a1.w);
}

// ---------------- fp8-MFMA GEMM (layers 0..16): T8 = H8 @ W8 + b ----------------
// H and W stay fp8 end-to-end: no unpack, 26 KB LDS -> ~2x occupancy of the f16 path.

__global__ __launch_bounds__(256) void gemm8_k(const unsigned char* __restrict__ H8,
                                               const unsigned char* __restrict__ W8,
                                               const float* __restrict__ b,
                                               unsigned char* __restrict__ T8) {
    __shared__ unsigned char Ws8[HF * W8_STRIDE];  // 17 KB, [n][k]
    __shared__ unsigned char Hs8[64 * W8_STRIDE];  // 8.5 KB, [row][k]; reused for C staging
    int t = threadIdx.x;
    int rbase = blockIdx.x * 64;
    int u16 = t & 15;   // 8-byte unit within a 128 B row
    int rg  = t >> 4;

#pragma unroll
    for (int p = 0; p < 8; p++) {
        int n = p * 16 + rg;
        *(uint2*)&Ws8[n * W8_STRIDE + u16 * 8] = *(const uint2*)&W8[(size_t)n * HF + u16 * 8];
    }
#pragma unroll
    for (int p = 0; p < 4; p++) {
        int rl = p * 16 + rg;
        int row = rbase + rl;
        if (row >= N_NODES) row = N_NODES - 1;
        *(uint2*)&Hs8[rl * W8_STRIDE + u16 * 8] = *(const uint2*)&H8[(size_t)row * HF + u16 * 8];
    }
    __syncthreads();

    int lane = t & 63;
    int w    = t >> 6;
    int wr   = w * 16;
    int m16  = lane & 15;
    int q    = lane >> 4;

    long af[4];
#pragma unroll
    for (int kc = 0; kc < 4; kc++)
        af[kc] = *(const long*)&Hs8[(wr + m16) * W8_STRIDE + kc * 32 + q * 8];

    f32x4 acc[8];
#pragma unroll
    for (int nt = 0; nt < 8; nt++) {
        float bv = b[nt * 16 + m16];
        acc[nt] = (f32x4){bv, bv, bv, bv};
#pragma unroll
        for (int kc = 0; kc < 4; kc++) {
            long bf = *(const long*)&Ws8[(nt * 16 + m16) * W8_STRIDE + kc * 32 + q * 8];
            acc[nt] = __builtin_amdgcn_mfma_f32_16x16x32_fp8_fp8(af[kc], bf, acc[nt], 0, 0, 0);
        }
    }
    __syncthreads();  // done reading Hs8; reuse for C staging [row][n] (fp8 bytes)

#pragma unroll
    for (int nt = 0; nt < 8; nt++)
#pragma unroll
        for (int r = 0; r < 4; r++) {
            float v = lrelu(acc[nt][r]) == 0.f ? acc[nt][r] : acc[nt][r];  // no-op; keep raw
            Hs8[(wr + q * 4 + r) * W8_STRIDE + nt * 16 + m16] =
                (unsigned char)(__builtin_amdgcn_cvt_pk_fp8_f32(v, v, 0, false) & 0xFF);
        }
    __syncthreads();

#pragma unroll
    for (int p = 0; p < 4; p++) {
        int rl = p * 16 + rg;
        int row = rbase + rl;
        if (row < N_NODES)
            *(uint2*)&T8[(size_t)row * HF + u16 * 8] = *(uint2*)&Hs8[rl * W8_STRIDE + u16 * 8];
    }
}

// ---------------- f16-MFMA GEMM (layers 17,18): T = H @ W + b ----------------

template <bool FP8IN, bool FP8OUT>
__global__ __launch_bounds__(256) void gemm_mfma_k(const void* __restrict__ Hin,
                                                   const __half* __restrict__ Wt,
                                                   const float* __restrict__ b,
                                                   void* __restrict__ Tout) {
    __shared__ __half Ws[HF * WS_STRIDE];  // 34 KB, [n][k]
    __shared__ __half Hs[64 * WS_STRIDE];  // 17 KB, [row][k]; reused for C staging
    int t = threadIdx.x;
    int rbase = blockIdx.x * 64;
    int u16 = t & 15;
    int rg  = t >> 4;

#pragma unroll
    for (int p = 0; p < 8; p++) {
        int n = p * 16 + rg;
        *(float4*)&Ws[n * WS_STRIDE + u16 * 8] = *(const float4*)&Wt[(size_t)n * HF + u16 * 8];
    }
#pragma unroll
    for (int p = 0; p < 4; p++) {
        int rl = p * 16 + rg;
        int row = rbase + rl;
        if (row >= N_NODES) row = N_NODES - 1;
        if (FP8IN) {
            uint2 hv8 = *(const uint2*)&((const unsigned char*)Hin)[(size_t)row * HF + u16 * 8];
            f32x2 a0 = __builtin_amdgcn_cvt_pk_f32_fp8((int)hv8.x, false);
            f32x2 a1 = __builtin_amdgcn_cvt_pk_f32_fp8((int)hv8.x, true);
            f32x2 a2 = __builtin_amdgcn_cvt_pk_f32_fp8((int)hv8.y, false);
            f32x2 a3 = __builtin_amdgcn_cvt_pk_f32_fp8((int)hv8.y, true);
            h4 o0, o1;
            o0.a = __floats2half2_rn(a0.x, a0.y); o0.b = __floats2half2_rn(a1.x, a1.y);
            o1.a = __floats2half2_rn(a2.x, a2.y); o1.b = __floats2half2_rn(a3.x, a3.y);
            float4 pk;
            ((h4*)&pk)[0] = o0;
            *(h4*)((char*)&pk + 8) = o1;
            *(float4*)&Hs[rl * WS_STRIDE + u16 * 8] = pk;
        } else {
            *(float4*)&Hs[rl * WS_STRIDE + u16 * 8] =
                *(const float4*)&((const __half*)Hin)[(size_t)row * HF + u16 * 8];
        }
    }
    __syncthreads();

    int lane = t & 63;
    int w    = t >> 6;
    int wr   = w * 16;
    int m16  = lane & 15;
    int q    = lane >> 4;

    f16x8 af[4];
#pragma unroll
    for (int kc = 0; kc < 4; kc++)
        af[kc] = *(const f16x8*)&Hs[(wr + m16) * WS_STRIDE + kc * 32 + q * 8];

    f32x4 acc[8];
#pragma unroll
    for (int nt = 0; nt < 8; nt++) {
        float bv = b[nt * 16 + m16];
        acc[nt] = (f32x4){bv, bv, bv, bv};
#pragma unroll
        for (int kc = 0; kc < 4; kc++) {
            f16x8 bf = *(const f16x8*)&Ws[(nt * 16 + m16) * WS_STRIDE + kc * 32 + q * 8];
            acc[nt] = __builtin_amdgcn_mfma_f32_16x16x32_f16(af[kc], bf, acc[nt], 0, 0, 0);
        }
    }
    __syncthreads();

#pragma unroll
    for (int nt = 0; nt < 8; nt++)
#pragma unroll
        for (int r = 0; r < 4; r++)
            Hs[(wr + q * 4 + r) * WS_STRIDE + nt * 16 + m16] = __float2half(acc[nt][r]);
    __syncthreads();

#pragma unroll
    for (int p = 0; p < 4; p++) {
        int rl = p * 16 + rg;
        int row = rbase + rl;
        if (row < N_NODES) {
            float4 cv = *(float4*)&Hs[rl * WS_STRIDE + u16 * 8];
            if (FP8OUT) {
                __half2* hp = (__half2*)&cv;
                float2 f0 = __half22float2(hp[0]);
                float2 f1 = __half22float2(hp[1]);
                float2 f2 = __half22float2(hp[2]);
                float2 f3 = __half22float2(hp[3]);
                uint2 o;
                o.x = pack_fp8x4(f0.x, f0.y, f1.x, f1.y);
                o.y = pack_fp8x4(f2.x, f2.y, f3.x, f3.y);
                *(uint2*)&((unsigned char*)Tout)[(size_t)row * HF + u16 * 8] = o;
            } else {
                *(float4*)&((__half*)Tout)[(size_t)row * HF + u16 * 8] = cv;
            }
        }
    }
}

// ---------------- aggregation: FOUR nodes per wave; 4-byte edge records ----------------

template <bool FP8IN, bool FP8OUT>
__global__ __launch_bounds__(256) void agg4_k(const void* __restrict__ Tin,
                                              void* __restrict__ O,
                                              const int* __restrict__ rowptr,
                                              const unsigned* __restrict__ edg) {
    int gw = blockIdx.x * 4 + (threadIdx.x >> 6);
    int v0 = gw * 4;
    if (v0 >= N_NODES) return;
    int lane = threadIdx.x & 63;
    int q  = lane >> 4;
    int li = lane & 15;

    int rp = rowptr[v0 + min(lane, 4)];
    int r0 = __shfl(rp, 0, 64), r1 = __shfl(rp, 1, 64), r2 = __shfl(rp, 2, 64);
    int r3 = __shfl(rp, 3, 64), r4 = __shfl(rp, 4, 64);
    int e0 = __shfl(rp, q, 64);
    int e1 = __shfl(rp, q + 1, 64);
    int degmax = max(max(r1 - r0, r2 - r1), max(r3 - r2, r4 - r3));
    int nb = (degmax + 15) >> 4;

    const uint2* T8  = (const uint2*)Tin;   // fp8 row = 16 x uint2
    const uint4* T16 = (const uint4*)Tin;   // fp16 row = 16 x uint4

    float acc[8] = {0.f, 0.f, 0.f, 0.f, 0.f, 0.f, 0.f, 0.f};

    for (int eb = 0; eb < nb; eb++) {
        int idx = e0 + eb * 16 + li;
        bool ok = idx < e1;
        unsigned rec = edg[ok ? idx : 0];
        if (!ok) rec &= 0xFFFFu;  // zero the fp16 weight
        int sb = q << 4;
#pragma unroll
        for (int g = 0; g < 2; g++) {
            int   ss[8];
            float ww[8];
#pragma unroll
            for (int u = 0; u < 8; u++) {
                int rv = __shfl((int)rec, sb + g * 8 + u, 64);
                ss[u] = rv & 0xFFFF;
                ww[u] = __half2float(__ushort_as_half((unsigned short)((unsigned)rv >> 16)));
            }
            if (FP8IN) {
                uint2 gv[8];
#pragma unroll
                for (int u = 0; u < 8; u++)
                    gv[u] = T8[(size_t)ss[u] * 16 + li];
#pragma unroll
                for (int u = 0; u < 8; u++) {
                    f32x2 p0 = __builtin_amdgcn_cvt_pk_f32_fp8((int)gv[u].x, false);
                    f32x2 p1 = __builtin_amdgcn_cvt_pk_f32_fp8((int)gv[u].x, true);
                    f32x2 p2 = __builtin_amdgcn_cvt_pk_f32_fp8((int)gv[u].y, false);
                    f32x2 p3 = __builtin_amdgcn_cvt_pk_f32_fp8((int)gv[u].y, true);
                    acc[0] = fmaf(p0.x, ww[u], acc[0]);
                    acc[1] = fmaf(p0.y, ww[u], acc[1]);
                    acc[2] = fmaf(p1.x, ww[u], acc[2]);
                    acc[3] = fmaf(p1.y, ww[u], acc[3]);
                    acc[4] = fmaf(p2.x, ww[u], acc[4]);
                    acc[5] = fmaf(p2.y, ww[u], acc[5]);
                    acc[6] = fmaf(p3.x, ww[u], acc[6]);
                    acc[7] = fmaf(p3.y, ww[u], acc[7]);
                }
            } else {
                uint4 gv[8];
#pragma unroll
                for (int u = 0; u < 8; u++)
                    gv[u] = T16[(size_t)ss[u] * 16 + li];
#pragma unroll
                for (int u = 0; u < 8; u++) {
                    __half2* hp = (__half2*)&gv[u];
                    float2 p0 = __half22float2(hp[0]);
                    float2 p1 = __half22float2(hp[1]);
                    float2 p2 = __half22float2(hp[2]);
                    float2 p3 = __half22float2(hp[3]);
                    acc[0] = fmaf(p0.x, ww[u], acc[0]);
                    acc[1] = fmaf(p0.y, ww[u], acc[1]);
                    acc[2] = fmaf(p1.x, ww[u], acc[2]);
                    acc[3] = fmaf(p1.y, ww[u], acc[3]);
                    acc[4] = fmaf(p2.x, ww[u], acc[4]);
                    acc[5] = fmaf(p2.y, ww[u], acc[5]);
                    acc[6] = fmaf(p3.x, ww[u], acc[6]);
                    acc[7] = fmaf(p3.y, ww[u], acc[7]);
                }
            }
        }
    }
    int v = v0 + q;
    if (FP8OUT) {
        uint2 o;
        o.x = pack_fp8x4(lrelu(acc[0]), lrelu(acc[1]), lrelu(acc[2]), lrelu(acc[3]));
        o.y = pack_fp8x4(lrelu(acc[4]), lrelu(acc[5]), lrelu(acc[6]), lrelu(acc[7]));
        ((uint2*)O)[(size_t)v * 16 + li] = o;
    } else {
        h4 oa, ob;
        oa.a = __floats2half2_rn(lrelu(acc[0]), lrelu(acc[1]));
        oa.b = __floats2half2_rn(lrelu(acc[2]), lrelu(acc[3]));
        ob.a = __floats2half2_rn(lrelu(acc[4]), lrelu(acc[5]));
        ob.b = __floats2half2_rn(lrelu(acc[6]), lrelu(acc[7]));
        uint4 ov;
        ((h4*)&ov)[0] = oa;
        *(h4*)((char*)&ov + 8) = ob;
        ((uint4*)O)[(size_t)v * 16 + li] = ov;
    }
}

// ---------------- output layer: out = H(fp16) @ Wfc + bfc (N=4) ----------------

__global__ void fc_k(const __half* __restrict__ H, const float* __restrict__ W,
                     const float* __restrict__ b, float* __restrict__ out) {
    int r = blockIdx.x * 256 + threadIdx.x;
    if (r >= N_NODES) return;
    float4 acc = *(const float4*)b;
    const h4* hp = (const h4*)(H + (size_t)r * HF);
    const float4* w4 = (const float4*)W;
#pragma unroll
    for (int k4 = 0; k4 < 32; k4++) {
        h4 hh = hp[k4];
        float2 p0 = __half22float2(hh.a);
        float2 p1 = __half22float2(hh.b);
        float4 wa = w4[k4 * 4 + 0], wb = w4[k4 * 4 + 1];
        float4 wc = w4[k4 * 4 + 2], wd = w4[k4 * 4 + 3];
        acc.x = fmaf(p0.x, wa.x, acc.x); acc.y = fmaf(p0.x, wa.y, acc.y);
        acc.z = fmaf(p0.x, wa.z, acc.z); acc.w = fmaf(p0.x, wa.w, acc.w);
        acc.x = fmaf(p0.y, wb.x, acc.x); acc.y = fmaf(p0.y, wb.y, acc.y);
        acc.z = fmaf(p0.y, wb.z, acc.z); acc.w = fmaf(p0.y, wb.w, acc.w);
        acc.x = fmaf(p1.x, wc.x, acc.x); acc.y = fmaf(p1.x, wc.y, acc.y);
        acc.z = fmaf(p1.x, wc.z, acc.z); acc.w = fmaf(p1.x, wc.w, acc.w);
        acc.x = fmaf(p1.y, wd.x, acc.x); acc.y = fmaf(p1.y, wd.y, acc.y);
        acc.z = fmaf(p1.y, wd.z, acc.z); acc.w = fmaf(p1.y, wd.w, acc.w);
    }
    *(float4*)&out[r * NC] = acc;
}

// ---------------- driver ----------------

extern "C" void kernel_launch(void* const* d_in, const int* in_sizes, int n_in,
                              void* d_out, int out_size, void* d_ws, size_t ws_size,
                              hipStream_t stream) {
    const float* X   = (const float*)d_in[0];
    const int*   EI  = (const int*)d_in[1];
    const float* EA  = (const float*)d_in[2];
    const float* Win = (const float*)d_in[3];
    const float* bin = (const float*)d_in[4];
    const float* Wh  = (const float*)d_in[5];
    const float* bh  = (const float*)d_in[6];
    const float* Wfc = (const float*)d_in[7];
    const float* bfc = (const float*)d_in[8];
    float* out = (float*)d_out;
    const int* src = EI;
    const int* dst = EI + N_EDGES;

    char* ws = (char*)d_ws;
    size_t off = 0;
    void*     O    = (void*)(ws + off);     off += (size_t)N_NODES * HF * 2;
    void*     T    = (void*)(ws + off);     off += (size_t)N_NODES * HF * 2;
    __half*   Wt   = (__half*)(ws + off);   off += (size_t)NHL * HF * HF * 2;
    unsigned* W8   = (unsigned*)(ws + off); off += (size_t)NHL * HF * HF;
    unsigned* edg  = (unsigned*)(ws + off); off += (size_t)N_EDGES * 4;
    int* rowptr = (int*)(ws + off);   off += (((size_t)(N_NODES + 1) * 4 + 15) / 16) * 16;
    int* cnt    = (int*)(ws + off);   off += (size_t)N_NODES * 4;
    int* fill   = (int*)(ws + off);   off += (size_t)N_NODES * 4;
    float* dinv = (float*)(ws + off); off += (size_t)N_NODES * 4;

    hipMemsetAsync(cnt, 0, N_NODES * 4, stream);
    hipMemsetAsync(fill, 0, N_NODES * 4, stream);
    count_deg_k<<<(N_EDGES + 255) / 256, 256, 0, stream>>>(dst, cnt);
    scan_k<<<1, 1024, 0, stream>>>(cnt, rowptr, dinv);
    fill_k<<<(N_EDGES + 255) / 256, 256, 0, stream>>>(src, dst, EA, rowptr, fill, edg, dinv);
    wconv_k<<<(NHL * HF * HF + 255) / 256, 256, 0, stream>>>(Wh, Wt);
    wconv8_k<<<(NHL * HF * HF / 4 + 255) / 256, 256, 0, stream>>>(Wh, W8);

    const int aggg  = (N_NODES / 4 + 3) / 4;
    const int gemmg = (N_NODES + 63) / 64;

    // input layer: fp8 T, fp8 O
    gemm_in_k<<<(N_NODES + 15) / 16, 256, 0, stream>>>(X, Win, bin, (unsigned*)T);
    agg4_k<true, true><<<aggg, 256, 0, stream>>>(T, O, rowptr, edg);
    // hidden gemms 0..16: fp8 MFMA (W fp8, distance >= 2)
    for (int l = 0; l < 17; l++) {
        gemm8_k<<<gemmg, 256, 0, stream>>>(
            (const unsigned char*)O, (const unsigned char*)(W8 + (size_t)l * HF * HF / 4),
            bh + (size_t)l * HF, (unsigned char*)T);
        agg4_k<true, true><<<aggg, 256, 0, stream>>>(T, O, rowptr, edg);
    }
    // gemm 17 (distance 1): f16 MFMA, fp8 in/out; agg emits fp16 O
    gemm_mfma_k<true, true><<<gemmg, 256, 0, stream>>>(
        O, Wt + (size_t)17 * HF * HF, bh + (size_t)17 * HF, T);
    agg4_k<true, false><<<aggg, 256, 0, stream>>>(T, O, rowptr, edg);
    // gemm 18 (distance 0): all fp16
    gemm_mfma_k<false, false><<<gemmg, 256, 0, stream>>>(
        O, Wt + (size_t)18 * HF * HF, bh + (size_t)18 * HF, T);
    agg4_k<false, false><<<aggg, 256, 0, stream>>>(T, O, rowptr, edg);
    fc_k<<<(N_NODES + 255) / 256, 256, 0, stream>>>((const __half*)O, Wfc, bfc, out);
}

// Round 19
// 695.846 us; speedup vs baseline: 1.0241x; 1.0241x over previous
//
#include <hip/hip_runtime.h>
#include <hip/hip_fp16.h>

#define N_NODES 50000
#define N_EDGES 600000
#define IN_F 16
#define HF 128
#define NC 4
#define NHL 19
#define N_FP8_LAYERS 18  // gemms 0..17 fp8 T/H; only T_18 (distance 0) stays fp16
#define WS_STRIDE 136    // 128 f16 + 8 pad = 272 B rows

__device__ __forceinline__ float lrelu(float x) { return x > 0.f ? x : 0.01f * x; }

struct h4 { __half2 a, b; };  // 8 bytes = 4 fp16 feats

typedef _Float16 f16;
typedef _Float16 f16x8 __attribute__((ext_vector_type(8)));
typedef float    f32x4 __attribute__((ext_vector_type(4)));
typedef float    f32x2 __attribute__((ext_vector_type(2)));

__device__ __forceinline__ unsigned pack_fp8x4(float a, float b, float c, float d) {
    int r = __builtin_amdgcn_cvt_pk_fp8_f32(a, b, 0, false);
    r = __builtin_amdgcn_cvt_pk_fp8_f32(c, d, r, true);
    return (unsigned)r;
}

// ---------------- CSR build ----------------

__global__ void count_deg_k(const int* __restrict__ dst, int* __restrict__ cnt) {
    int e = blockIdx.x * 256 + threadIdx.x;
    if (e < N_EDGES) atomicAdd(&cnt[dst[e]], 1);
}

// single-block exclusive scan via wave shuffles; also emits dinv
__global__ void scan_k(const int* __restrict__ cnt, int* __restrict__ rowptr,
                       float* __restrict__ dinv) {
    __shared__ int wsum[16];
    __shared__ int carry_s;
    int t = threadIdx.x;
    int lane = t & 63, wid = t >> 6;
    if (t == 0) carry_s = 0;
    __syncthreads();
    for (int base = 0; base < N_NODES; base += 4096) {
        int idx = base + t * 4;
        int4 v = make_int4(0, 0, 0, 0);
        if (idx + 3 < N_NODES) v = *(const int4*)&cnt[idx];
        else {
            if (idx     < N_NODES) v.x = cnt[idx];
            if (idx + 1 < N_NODES) v.y = cnt[idx + 1];
            if (idx + 2 < N_NODES) v.z = cnt[idx + 2];
            if (idx + 3 < N_NODES) v.w = cnt[idx + 3];
        }
        if (idx + 3 < N_NODES) {
            float4 dv = make_float4(1.f / fmaxf((float)v.x, 1.f), 1.f / fmaxf((float)v.y, 1.f),
                                    1.f / fmaxf((float)v.z, 1.f), 1.f / fmaxf((float)v.w, 1.f));
            *(float4*)&dinv[idx] = dv;
        } else {
            if (idx     < N_NODES) dinv[idx]     = 1.f / fmaxf((float)v.x, 1.f);
            if (idx + 1 < N_NODES) dinv[idx + 1] = 1.f / fmaxf((float)v.y, 1.f);
            if (idx + 2 < N_NODES) dinv[idx + 2] = 1.f / fmaxf((float)v.z, 1.f);
            if (idx + 3 < N_NODES) dinv[idx + 3] = 1.f / fmaxf((float)v.w, 1.f);
        }
        int s1 = v.x + v.y, s2 = s1 + v.z, total = s2 + v.w;
        int sc = total;
#pragma unroll
        for (int off = 1; off < 64; off <<= 1) {
            int u = __shfl_up(sc, off, 64);
            if (lane >= off) sc += u;
        }
        if (lane == 63) wsum[wid] = sc;
        __syncthreads();
        if (t < 16) {
            int w = wsum[t];
#pragma unroll
            for (int off = 1; off < 16; off <<= 1) {
                int u = __shfl_up(w, off, 64);
                if (t >= off) w += u;
            }
            wsum[t] = w;
        }
        __syncthreads();
        int prefix = carry_s + (wid > 0 ? wsum[wid - 1] : 0) + (sc - total);
        if (idx     < N_NODES) rowptr[idx]     = prefix;
        if (idx + 1 < N_NODES) rowptr[idx + 1] = prefix + v.x;
        if (idx + 2 < N_NODES) rowptr[idx + 2] = prefix + s1;
        if (idx + 3 < N_NODES) rowptr[idx + 3] = prefix + s2;
        __syncthreads();
        if (t == 0) carry_s += wsum[15];
        __syncthreads();
    }
    if (t == 0) rowptr[N_NODES] = carry_s;
}

// fill CSR: one int2 {src, bitcast(ea*dinv[dst])} store per edge
__global__ void fill_k(const int* __restrict__ src, const int* __restrict__ dst,
                       const float* __restrict__ ea, const int* __restrict__ rowptr,
                       int* __restrict__ fill, int2* __restrict__ edg,
                       const float* __restrict__ dinv) {
    int e = blockIdx.x * 256 + threadIdx.x;
    if (e < N_EDGES) {
        int d = dst[e];
        int pos = rowptr[d] + atomicAdd(&fill[d], 1);
        edg[pos] = make_int2(src[e], __float_as_int(ea[e] * dinv[d]));
    }
}

// ---------------- W convert: Wh[l][k][n] fp32 -> Wt[l][n][k] fp16 ----------------

__global__ void wconv_k(const float* __restrict__ Wh, __half* __restrict__ Wt) {
    int idx = blockIdx.x * 256 + threadIdx.x;
    if (idx >= NHL * HF * HF) return;
    int l = idx / (HF * HF);
    int r = idx - l * (HF * HF);
    int n = r >> 7;
    int k = r & 127;
    Wt[idx] = __float2half(Wh[(size_t)l * HF * HF + k * HF + n]);
}

// ---------------- input GEMM: T8[50000x128](fp8) = X[50000x16] @ W[16x128] + b ----------------

__global__ void gemm_in_k(const float* __restrict__ X, const float* __restrict__ W,
                          const float* __restrict__ b, unsigned* __restrict__ T8) {
    __shared__ float Ws[IN_F * HF];  // 8 KB
    int t = threadIdx.x;
    ((float4*)Ws)[t]       = ((const float4*)W)[t];
    ((float4*)Ws)[t + 256] = ((const float4*)W)[t + 256];
    __syncthreads();
    int row = blockIdx.x * 16 + (t >> 4);
    if (row >= N_NODES) return;
    int tx = t & 15;
    int c0 = tx * 4, c1 = 64 + tx * 4;
    float4 a0 = *(const float4*)&b[c0];
    float4 a1 = *(const float4*)&b[c1];
    const float4* xr = (const float4*)(X + row * IN_F);
#pragma unroll
    for (int k4 = 0; k4 < 4; k4++) {
        float4 xv = xr[k4];
        const float* xp = (const float*)&xv;
#pragma unroll
        for (int kk = 0; kk < 4; kk++) {
            int k = k4 * 4 + kk;
            float4 w0 = *(const float4*)&Ws[k * HF + c0];
            float4 w1 = *(const float4*)&Ws[k * HF + c1];
            float xs = xp[kk];
            a0.x = fmaf(xs, w0.x, a0.x); a0.y = fmaf(xs, w0.y, a0.y);
            a0.z = fmaf(xs, w0.z, a0.z); a0.w = fmaf(xs, w0.w, a0.w);
            a1.x = fmaf(xs, w1.x, a1.x); a1.y = fmaf(xs, w1.y, a1.y);
            a1.z = fmaf(xs, w1.z, a1.z); a1.w = fmaf(xs, w1.w, a1.w);
        }
    }
    T8[(size_t)row * 32 + tx]      = pack_fp8x4(a0.x, a0.y, a0.z, a0.w);
    T8[(size_t)row * 32 + 16 + tx] = pack_fp8x4(a1.x, a1.y, a1.z, a1.w);
}

// ---------------- hidden GEMM via MFMA f16: T = H @ W + b ----------------
// R11 form: W tile + H tile in LDS (W-from-global was R12's +10us/gemm mistake;
// fp8-MFMA with byte-wise epilogue was R18's +14us mistake — both reverted).

template <bool FP8IN, bool FP8OUT>
__global__ __launch_bounds__(256) void gemm_mfma_k(const void* __restrict__ Hin,
                                                   const __half* __restrict__ Wt,
                                                   const float* __restrict__ b,
                                                   void* __restrict__ Tout) {
    __shared__ __half Ws[HF * WS_STRIDE];  // 34 KB, [n][k]
    __shared__ __half Hs[64 * WS_STRIDE];  // 17 KB, [row][k]; reused for C staging
    int t = threadIdx.x;
    int rbase = blockIdx.x * 64;
    int u16 = t & 15;
    int rg  = t >> 4;

#pragma unroll
    for (int p = 0; p < 8; p++) {
        int n = p * 16 + rg;
        *(float4*)&Ws[n * WS_STRIDE + u16 * 8] = *(const float4*)&Wt[(size_t)n * HF + u16 * 8];
    }
#pragma unroll
    for (int p = 0; p < 4; p++) {
        int rl = p * 16 + rg;
        int row = rbase + rl;
        if (row >= N_NODES) row = N_NODES - 1;
        if (FP8IN) {
            uint2 hv8 = *(const uint2*)&((const unsigned char*)Hin)[(size_t)row * HF + u16 * 8];
            f32x2 a0 = __builtin_amdgcn_cvt_pk_f32_fp8((int)hv8.x, false);
            f32x2 a1 = __builtin_amdgcn_cvt_pk_f32_fp8((int)hv8.x, true);
            f32x2 a2 = __builtin_amdgcn_cvt_pk_f32_fp8((int)hv8.y, false);
            f32x2 a3 = __builtin_amdgcn_cvt_pk_f32_fp8((int)hv8.y, true);
            h4 o0, o1;
            o0.a = __floats2half2_rn(a0.x, a0.y); o0.b = __floats2half2_rn(a1.x, a1.y);
            o1.a = __floats2half2_rn(a2.x, a2.y); o1.b = __floats2half2_rn(a3.x, a3.y);
            float4 pk;
            ((h4*)&pk)[0] = o0;
            *(h4*)((char*)&pk + 8) = o1;
            *(float4*)&Hs[rl * WS_STRIDE + u16 * 8] = pk;
        } else {
            *(float4*)&Hs[rl * WS_STRIDE + u16 * 8] =
                *(const float4*)&((const __half*)Hin)[(size_t)row * HF + u16 * 8];
        }
    }
    __syncthreads();

    int lane = t & 63;
    int w    = t >> 6;
    int wr   = w * 16;
    int m16  = lane & 15;
    int q    = lane >> 4;

    f16x8 af[4];
#pragma unroll
    for (int kc = 0; kc < 4; kc++)
        af[kc] = *(const f16x8*)&Hs[(wr + m16) * WS_STRIDE + kc * 32 + q * 8];

    f32x4 acc[8];
#pragma unroll
    for (int nt = 0; nt < 8; nt++) {
        float bv = b[nt * 16 + m16];
        acc[nt] = (f32x4){bv, bv, bv, bv};
#pragma unroll
        for (int kc = 0; kc < 4; kc++) {
            f16x8 bf = *(const f16x8*)&Ws[(nt * 16 + m16) * WS_STRIDE + kc * 32 + q * 8];
            acc[nt] = __builtin_amdgcn_mfma_f32_16x16x32_f16(af[kc], bf, acc[nt], 0, 0, 0);
        }
    }
    __syncthreads();  // done reading Hs; reuse for C staging [row][n] (fp16)

#pragma unroll
    for (int nt = 0; nt < 8; nt++)
#pragma unroll
        for (int r = 0; r < 4; r++)
            Hs[(wr + q * 4 + r) * WS_STRIDE + nt * 16 + m16] = __float2half(acc[nt][r]);
    __syncthreads();

#pragma unroll
    for (int p = 0; p < 4; p++) {
        int rl = p * 16 + rg;
        int row = rbase + rl;
        if (row < N_NODES) {
            float4 cv = *(float4*)&Hs[rl * WS_STRIDE + u16 * 8];  // 8 halves
            if (FP8OUT) {
                __half2* hp = (__half2*)&cv;
                float2 f0 = __half22float2(hp[0]);
                float2 f1 = __half22float2(hp[1]);
                float2 f2 = __half22float2(hp[2]);
                float2 f3 = __half22float2(hp[3]);
                uint2 o;
                o.x = pack_fp8x4(f0.x, f0.y, f1.x, f1.y);
                o.y = pack_fp8x4(f2.x, f2.y, f3.x, f3.y);
                *(uint2*)&((unsigned char*)Tout)[(size_t)row * HF + u16 * 8] = o;
            } else {
                *(float4*)&((__half*)Tout)[(size_t)row * HF + u16 * 8] = cv;
            }
        }
    }
}

// ---------------- aggregation: FOUR nodes per wave ----------------
// fp8: 8 B/lane (16 lanes/row); fp16: 16 B/lane. Quarter q = node v0+q, li = lane&15.

template <bool FP8IN, bool FP8OUT>
__global__ __launch_bounds__(256) void agg4_k(const void* __restrict__ Tin,
                                              void* __restrict__ O,
                                              const int* __restrict__ rowptr,
                                              const int2* __restrict__ edg) {
    int gw = blockIdx.x * 4 + (threadIdx.x >> 6);
    int v0 = gw * 4;
    if (v0 >= N_NODES) return;
    int lane = threadIdx.x & 63;
    int q  = lane >> 4;
    int li = lane & 15;

    int rp = rowptr[v0 + min(lane, 4)];
    int r0 = __shfl(rp, 0, 64), r1 = __shfl(rp, 1, 64), r2 = __shfl(rp, 2, 64);
    int r3 = __shfl(rp, 3, 64), r4 = __shfl(rp, 4, 64);
    int e0 = __shfl(rp, q, 64);
    int e1 = __shfl(rp, q + 1, 64);
    int degmax = max(max(r1 - r0, r2 - r1), max(r3 - r2, r4 - r3));
    int nb = (degmax + 15) >> 4;

    const uint2* T8  = (const uint2*)Tin;   // fp8 row = 16 x uint2
    const uint4* T16 = (const uint4*)Tin;   // fp16 row = 16 x uint4

    float acc[8] = {0.f, 0.f, 0.f, 0.f, 0.f, 0.f, 0.f, 0.f};

    for (int eb = 0; eb < nb; eb++) {
        int idx = e0 + eb * 16 + li;
        bool ok = idx < e1;
        int2 rec = edg[ok ? idx : 0];
        if (!ok) rec.y = 0;
        int sb = q << 4;
#pragma unroll
        for (int g = 0; g < 2; g++) {
            int   ss[8];
            float ww[8];
#pragma unroll
            for (int u = 0; u < 8; u++) {
                int sl = sb + g * 8 + u;
                ss[u] = __shfl(rec.x, sl, 64);
                ww[u] = __int_as_float(__shfl(rec.y, sl, 64));
            }
            if (FP8IN) {
                uint2 gv[8];
#pragma unroll
                for (int u = 0; u < 8; u++)
                    gv[u] = T8[(size_t)ss[u] * 16 + li];
#pragma unroll
                for (int u = 0; u < 8; u++) {
                    f32x2 p0 = __builtin_amdgcn_cvt_pk_f32_fp8((int)gv[u].x, false);
                    f32x2 p1 = __builtin_amdgcn_cvt_pk_f32_fp8((int)gv[u].x, true);
                    f32x2 p2 = __builtin_amdgcn_cvt_pk_f32_fp8((int)gv[u].y, false);
                    f32x2 p3 = __builtin_amdgcn_cvt_pk_f32_fp8((int)gv[u].y, true);
                    acc[0] = fmaf(p0.x, ww[u], acc[0]);
                    acc[1] = fmaf(p0.y, ww[u], acc[1]);
                    acc[2] = fmaf(p1.x, ww[u], acc[2]);
                    acc[3] = fmaf(p1.y, ww[u], acc[3]);
                    acc[4] = fmaf(p2.x, ww[u], acc[4]);
                    acc[5] = fmaf(p2.y, ww[u], acc[5]);
                    acc[6] = fmaf(p3.x, ww[u], acc[6]);
                    acc[7] = fmaf(p3.y, ww[u], acc[7]);
                }
            } else {
                uint4 gv[8];
#pragma unroll
                for (int u = 0; u < 8; u++)
                    gv[u] = T16[(size_t)ss[u] * 16 + li];
#pragma unroll
                for (int u = 0; u < 8; u++) {
                    __half2* hp = (__half2*)&gv[u];
                    float2 p0 = __half22float2(hp[0]);
                    float2 p1 = __half22float2(hp[1]);
                    float2 p2 = __half22float2(hp[2]);
                    float2 p3 = __half22float2(hp[3]);
                    acc[0] = fmaf(p0.x, ww[u], acc[0]);
                    acc[1] = fmaf(p0.y, ww[u], acc[1]);
                    acc[2] = fmaf(p1.x, ww[u], acc[2]);
                    acc[3] = fmaf(p1.y, ww[u], acc[3]);
                    acc[4] = fmaf(p2.x, ww[u], acc[4]);
                    acc[5] = fmaf(p2.y, ww[u], acc[5]);
                    acc[6] = fmaf(p3.x, ww[u], acc[6]);
                    acc[7] = fmaf(p3.y, ww[u], acc[7]);
                }
            }
        }
    }
    int v = v0 + q;
    if (FP8OUT) {
        uint2 o;
        o.x = pack_fp8x4(lrelu(acc[0]), lrelu(acc[1]), lrelu(acc[2]), lrelu(acc[3]));
        o.y = pack_fp8x4(lrelu(acc[4]), lrelu(acc[5]), lrelu(acc[6]), lrelu(acc[7]));
        ((uint2*)O)[(size_t)v * 16 + li] = o;
    } else {
        h4 oa, ob;
        oa.a = __floats2half2_rn(lrelu(acc[0]), lrelu(acc[1]));
        oa.b = __floats2half2_rn(lrelu(acc[2]), lrelu(acc[3]));
        ob.a = __floats2half2_rn(lrelu(acc[4]), lrelu(acc[5]));
        ob.b = __floats2half2_rn(lrelu(acc[6]), lrelu(acc[7]));
        uint4 ov;
        ((h4*)&ov)[0] = oa;
        *(h4*)((char*)&ov + 8) = ob;
        ((uint4*)O)[(size_t)v * 16 + li] = ov;
    }
}

// ---------------- output layer: out = H(fp16) @ Wfc + bfc (N=4) ----------------

__global__ void fc_k(const __half* __restrict__ H, const float* __restrict__ W,
                     const float* __restrict__ b, float* __restrict__ out) {
    int r = blockIdx.x * 256 + threadIdx.x;
    if (r >= N_NODES) return;
    float4 acc = *(const float4*)b;
    const h4* hp = (const h4*)(H + (size_t)r * HF);
    const float4* w4 = (const float4*)W;
#pragma unroll
    for (int k4 = 0; k4 < 32; k4++) {
        h4 hh = hp[k4];
        float2 p0 = __half22float2(hh.a);
        float2 p1 = __half22float2(hh.b);
        float4 wa = w4[k4 * 4 + 0], wb = w4[k4 * 4 + 1];
        float4 wc = w4[k4 * 4 + 2], wd = w4[k4 * 4 + 3];
        acc.x = fmaf(p0.x, wa.x, acc.x); acc.y = fmaf(p0.x, wa.y, acc.y);
        acc.z = fmaf(p0.x, wa.z, acc.z); acc.w = fmaf(p0.x, wa.w, acc.w);
        acc.x = fmaf(p0.y, wb.x, acc.x); acc.y = fmaf(p0.y, wb.y, acc.y);
        acc.z = fmaf(p0.y, wb.z, acc.z); acc.w = fmaf(p0.y, wb.w, acc.w);
        acc.x = fmaf(p1.x, wc.x, acc.x); acc.y = fmaf(p1.x, wc.y, acc.y);
        acc.z = fmaf(p1.x, wc.z, acc.z); acc.w = fmaf(p1.x, wc.w, acc.w);
        acc.x = fmaf(p1.y, wd.x, acc.x); acc.y = fmaf(p1.y, wd.y, acc.y);
        acc.z = fmaf(p1.y, wd.z, acc.z); acc.w = fmaf(p1.y, wd.w, acc.w);
    }
    *(float4*)&out[r * NC] = acc;
}

// ---------------- driver ----------------

extern "C" void kernel_launch(void* const* d_in, const int* in_sizes, int n_in,
                              void* d_out, int out_size, void* d_ws, size_t ws_size,
                              hipStream_t stream) {
    const float* X   = (const float*)d_in[0];
    const int*   EI  = (const int*)d_in[1];
    const float* EA  = (const float*)d_in[2];
    const float* Win = (const float*)d_in[3];
    const float* bin = (const float*)d_in[4];
    const float* Wh  = (const float*)d_in[5];
    const float* bh  = (const float*)d_in[6];
    const float* Wfc = (const float*)d_in[7];
    const float* bfc = (const float*)d_in[8];
    float* out = (float*)d_out;
    const int* src = EI;
    const int* dst = EI + N_EDGES;

    char* ws = (char*)d_ws;
    size_t off = 0;
    void*   O   = (void*)(ws + off);   off += (size_t)N_NODES * HF * 2;
    void*   T   = (void*)(ws + off);   off += (size_t)N_NODES * HF * 2;
    __half* Wt  = (__half*)(ws + off); off += (size_t)NHL * HF * HF * 2;
    int2* edg   = (int2*)(ws + off);  off += (size_t)N_EDGES * 8;
    int* rowptr = (int*)(ws + off);   off += (((size_t)(N_NODES + 1) * 4 + 15) / 16) * 16;
    int* cnt    = (int*)(ws + off);   off += (size_t)N_NODES * 4;
    int* fill   = (int*)(ws + off);   off += (size_t)N_NODES * 4;
    float* dinv = (float*)(ws + off); off += (size_t)N_NODES * 4;

    hipMemsetAsync(cnt, 0, N_NODES * 4, stream);
    hipMemsetAsync(fill, 0, N_NODES * 4, stream);
    count_deg_k<<<(N_EDGES + 255) / 256, 256, 0, stream>>>(dst, cnt);
    scan_k<<<1, 1024, 0, stream>>>(cnt, rowptr, dinv);
    fill_k<<<(N_EDGES + 255) / 256, 256, 0, stream>>>(src, dst, EA, rowptr, fill, edg, dinv);
    wconv_k<<<(NHL * HF * HF + 255) / 256, 256, 0, stream>>>(Wh, Wt);

    const int aggg  = (N_NODES / 4 + 3) / 4;  // 4 nodes/wave, 4 waves/block = 3125 blocks
    const int gemmg = (N_NODES + 63) / 64;

    // input layer: fp8 T, fp8 O
    gemm_in_k<<<(N_NODES + 15) / 16, 256, 0, stream>>>(X, Win, bin, (unsigned*)T);
    agg4_k<true, true><<<aggg, 256, 0, stream>>>(T, O, rowptr, edg);
    // hidden gemms 0..17: fp8 H in, fp8 T out; agg after gemm 17 emits fp16 O
    for (int l = 0; l < N_FP8_LAYERS; l++) {
        gemm_mfma_k<true, true><<<gemmg, 256, 0, stream>>>(
            O, Wt + (size_t)l * HF * HF, bh + (size_t)l * HF, T);
        if (l < N_FP8_LAYERS - 1)
            agg4_k<true, true><<<aggg, 256, 0, stream>>>(T, O, rowptr, edg);
        else
            agg4_k<true, false><<<aggg, 256, 0, stream>>>(T, O, rowptr, edg);
    }
    // tail hidden layer 18: all fp16 (distance 0 — protects fc input precision)
    for (int l = N_FP8_LAYERS; l < NHL; l++) {
        gemm_mfma_k<false, false><<<gemmg, 256, 0, stream>>>(
            O, Wt + (size_t)l * HF * HF, bh + (size_t)l * HF, T);
        agg4_k<false, false><<<aggg, 256, 0, stream>>>(T, O, rowptr, edg);
    }
    fc_k<<<(N_NODES + 255) / 256, 256, 0, stream>>>((const __half*)O, Wfc, bfc, out);
}